// Round 7
// baseline (127.425 us; speedup 1.0000x reference)
//
#include <hip/hip_runtime.h>
#include <hip/hip_bf16.h>
#include <stdint.h>

typedef unsigned short u16;
typedef __attribute__((ext_vector_type(8))) short short8;
typedef __attribute__((ext_vector_type(4))) float f32x4;
typedef __attribute__((ext_vector_type(16))) float f32x16;

#define NDIM 256
#define SDIM 128
#define DDIM 64
#define HDIM 32
#define PDIM 64
#define EPS 1e-5f

__device__ __forceinline__ u16 f2bf(float f) {
  union { float f; uint32_t u; } v; v.f = f;
  uint32_t r = v.u + 0x7fffu + ((v.u >> 16) & 1u);   // RNE
  return (u16)(r >> 16);
}

// ---------------- K1: LN + dual projection via MFMA ----------------
// grid 1024: block = (n = bid>>2, sq = bid&3 -> 32 s-rows). 256 thr = 4 waves.
// a_t/b_t rows stored PRE-SWIZZLED: element s of row c lands at byte position
// (s&64)|(((s>>3)&7)^(c&7))<<3|(s&7) within the 128-elem row (k_fused glds image).
__global__ __launch_bounds__(256, 4) void k_pre(
    const float* __restrict__ msa, const float* __restrict__ mask,
    const float* __restrict__ gamma, const float* __restrict__ beta,
    const float* __restrict__ Wa, const float* __restrict__ ba,
    const float* __restrict__ Wb, const float* __restrict__ bb,
    const float* __restrict__ Wo,
    u16* __restrict__ a_t, u16* __restrict__ b_t, u16* __restrict__ W_t)
{
  __shared__ u16 xs[32 * 64];        // [s][granule swizzled] 4KB X_norm bf16
  __shared__ u16 wt[64 * 64];        // [c][granule swizzled] 8KB W^T bf16
  __shared__ float psum[2][8][32];
  __shared__ float maskF[128];
  __shared__ float gbF[128];

  const int n = blockIdx.x >> 2, sq = blockIdx.x & 3;
  const int t = threadIdx.x, lane = t & 63, wv = t >> 6;
  const int l15 = lane & 15, quad = lane >> 4;

  if (t < 64) gbF[t] = gamma[t];
  else if (t < 128) gbF[t] = beta[t - 64];
  else maskF[t - 128] = mask[(t - 128) * NDIM + n];

  // LN partials: row sl (0..31), d-slice pt8 (8 floats)
  const int sl = t >> 3, pt8 = t & 7;
  float x[8];
  {
    const float* xr = msa + ((sq * 32 + sl) * NDIM + n) * DDIM + pt8 * 8;
    float sum = 0.f, sq2 = 0.f;
    #pragma unroll
    for (int i = 0; i < 2; ++i) {
      const float4 q = ((const float4*)xr)[i];
      x[4*i] = q.x; x[4*i+1] = q.y; x[4*i+2] = q.z; x[4*i+3] = q.w;
      sum += q.x + q.y + q.z + q.w;
      sq2 += q.x*q.x + q.y*q.y + q.z*q.z + q.w*q.w;
    }
    psum[0][pt8][sl] = sum;
    psum[1][pt8][sl] = sq2;
  }

  // W^T: col c = t&63, d-slice (t>>6)*16
  {
    const int c = t & 63, ds = t >> 6;
    const int c31 = c & 31;
    const float* Wsel = (c >> 5) ? Wb : Wa;
    float w[16];
    #pragma unroll
    for (int i = 0; i < 16; ++i) w[i] = Wsel[(ds * 16 + i) * HDIM + c31];
    #pragma unroll
    for (int jj = 0; jj < 2; ++jj) {
      short8 v;
      #pragma unroll
      for (int k = 0; k < 8; ++k) v[k] = (short)f2bf(w[jj * 8 + k]);
      *(short8*)&wt[c * 64 + (((ds * 2 + jj) ^ (c & 7)) << 3)] = v;
    }
  }
  __syncthreads();

  // finish LN
  {
    float s0 = 0.f, s1 = 0.f;
    #pragma unroll
    for (int q = 0; q < 8; ++q) { s0 += psum[0][q][sl]; s1 += psum[1][q][sl]; }
    const float mu = s0 * (1.f / 64.f);
    const float var = s1 * (1.f / 64.f) - mu * mu;
    const float rs = rsqrtf(var + EPS);
    short8 v;
    #pragma unroll
    for (int k = 0; k < 8; ++k) {
      const int d = pt8 * 8 + k;
      v[k] = (short)f2bf((x[k] - mu) * rs * gbF[d] + gbF[64 + d]);
    }
    *(short8*)&xs[sl * 64 + ((pt8 ^ (sl & 7)) << 3)] = v;
  }
  float m2 = maskF[lane] + maskF[64 + lane];
  #pragma unroll
  for (int m = 32; m; m >>= 1) m2 += __shfl_xor(m2, m, 64);
  const float dinv = 1.f / fmaxf(m2, 1.f);
  __syncthreads();

  // projection: D[m=c][n=s], wave wv = c-tile [wv*16,+16); s covers 32 (2 nt)
  const f32x4 fz = {0.f, 0.f, 0.f, 0.f};
  f32x4 acc[2] = {fz, fz};
  short8 af[2];
  #pragma unroll
  for (int ks = 0; ks < 2; ++ks)
    af[ks] = *(const short8*)&wt[(wv * 16 + l15) * 64 + (((ks * 4 + quad) ^ (l15 & 7)) << 3)];
  #pragma unroll
  for (int nt = 0; nt < 2; ++nt)
    #pragma unroll
    for (int ks = 0; ks < 2; ++ks) {
      const short8 bf = *(const short8*)&xs[(nt * 16 + l15) * 64 + (((ks * 4 + quad) ^ (l15 & 7)) << 3)];
      acc[nt] = __builtin_amdgcn_mfma_f32_16x16x32_bf16(af[ks], bf, acc[nt], 0, 0, 0);
    }

  const float* bsel = (wv < 2) ? ba : bb;
  float bias_r[4];
  #pragma unroll
  for (int r = 0; r < 4; ++r) bias_r[r] = bsel[(wv & 1) * 16 + quad * 4 + r];
  u16* dstbase = ((wv < 2) ? a_t : b_t) + n * 4096;
  #pragma unroll
  for (int nt = 0; nt < 2; ++nt) {
    const int s = sq * 32 + nt * 16 + l15;
    const float mval = maskF[s];
    const float scale = (wv < 2) ? mval * dinv : mval;
    #pragma unroll
    for (int r = 0; r < 4; ++r) {
      const int c31 = (wv & 1) * 16 + quad * 4 + r;
      const int pos = (s & 64) | ((((s >> 3) & 7) ^ (c31 & 7)) << 3) | (s & 7);
      dstbase[c31 * 128 + pos] = f2bf((acc[nt][r] + bias_r[r]) * scale);
    }
  }

  // W_t2[hk>>3][p][hk&7] = bf16(Wo[hk][p])
  if (blockIdx.x < 256) {
    const int f = blockIdx.x * 256 + t;        // f = hk*64 + p
    const int p = f & 63, hk = f >> 6;
    W_t[(hk >> 3) * 512 + p * 8 + (hk & 7)] = f2bf(Wo[f]);
  }
}

// ---------------- K2: fused outer-product GEMM + Wo contraction ----------------
// grid (32 jT, 32 iT) x 1024 thr = 16 waves (wi 0..3 ih, wj 0..3 jk; 64x64/wave).
// Stage A: G-tile 256x256 over K=128 (2 chunks), glds staging, mfma_32x32x16
// swapped operands D[m=jk][n=ih], acc[2][2] f32x16 (64 regs/lane).
// Gs (64KB): row rij&31 pitch 1024 u16; elem hk at 16B-granule
// (hk>>3) ^ ((hk>>5)&7) ^ (rij&7), byte (hk&7)*2 — bank-floor dump & read.
// 2 passes of 32 rij: dump -> stage B (wave=(kq,ph,rh), 16x16x32, K-quarter,
// coalesced W_t2) -> red exchange [4][32][68] -> 1024-thr reduce+store.
__global__ __launch_bounds__(1024) void k_fused(
    const u16* __restrict__ a_t, const u16* __restrict__ b_t,
    const u16* __restrict__ W_t, const float* __restrict__ bo,
    float* __restrict__ out)
{
  __shared__ char smem[65536];
  u16* As = (u16*)smem;              // [256 ih][64 k] per chunk, 32KB
  u16* Bs = (u16*)(smem + 32768);    // [256 jk][64 k] per chunk, 32KB
  u16* Gs = (u16*)smem;              // [32 rij][1024 hk] swizzled, 64KB
  float* red = (float*)smem;         // [4 kq][32 rij][68] 34.8KB (aliases Gs tail-phase)

  const int tid = threadIdx.x, lane = tid & 63, wv = tid >> 6;   // 16 waves
  const int l15 = lane & 15, quad = lane >> 4;
  const int l31 = lane & 31, kh = lane >> 5;
  const int wi = wv >> 2, wj = wv & 3;
  const int jT = blockIdx.x, iT = blockIdx.y;

  const u16* gA = a_t + iT * 256 * SDIM;
  const u16* gB = b_t + jT * 256 * SDIM;

  f32x16 acc[2][2];                  // [jt][it]
  #pragma unroll
  for (int jt = 0; jt < 2; ++jt)
    #pragma unroll
    for (int it = 0; it < 2; ++it)
      #pragma unroll
      for (int r = 0; r < 16; ++r) acc[jt][it][r] = 0.f;

  const int sub8 = lane >> 3, g16 = lane & 7;

  for (int ch = 0; ch < 2; ++ch) {
    __syncthreads();
    #pragma unroll
    for (int i = 0; i < 2; ++i) {                // As rows [wv*16, +16)
      const int rbase = wv * 16 + i * 8;
      __builtin_amdgcn_global_load_lds(
          (const __attribute__((address_space(1))) void*)&gA[(rbase + sub8) * SDIM + ch * 64 + g16 * 8],
          (__attribute__((address_space(3))) void*)&As[rbase * 64], 16, 0, 0);
    }
    #pragma unroll
    for (int i = 0; i < 2; ++i) {                // Bs rows
      const int rbase = wv * 16 + i * 8;
      __builtin_amdgcn_global_load_lds(
          (const __attribute__((address_space(1))) void*)&gB[(rbase + sub8) * SDIM + ch * 64 + g16 * 8],
          (__attribute__((address_space(3))) void*)&Bs[rbase * 64], 16, 0, 0);
    }
    __syncthreads();
    #pragma unroll
    for (int ks = 0; ks < 4; ++ks) {             // K=16 steps (mfma32)
      const int g = ks * 2 + kh;
      short8 aop[2], bop[2];
      #pragma unroll
      for (int jt = 0; jt < 2; ++jt) {           // A-operand: jk rows from Bs
        const int row = wj * 64 + jt * 32 + l31;
        aop[jt] = *(const short8*)&Bs[row * 64 + ((g ^ (row & 7)) << 3)];
      }
      #pragma unroll
      for (int it = 0; it < 2; ++it) {           // B-operand: ih rows from As
        const int row = wi * 64 + it * 32 + l31;
        bop[it] = *(const short8*)&As[row * 64 + ((g ^ (row & 7)) << 3)];
      }
      #pragma unroll
      for (int jt = 0; jt < 2; ++jt)
        #pragma unroll
        for (int it = 0; it < 2; ++it)
          acc[jt][it] = __builtin_amdgcn_mfma_f32_32x32x16_bf16(aop[jt], bop[it], acc[jt][it], 0, 0, 0);
    }
  }

  #pragma unroll 1
  for (int pass = 0; pass < 2; ++pass) {
    __syncthreads();   // Gs region free
    if ((wi >> 1) == pass) {
      // dump: D32 layout col=l31 (=h), row m=(r&3)+8*(r>>2)+4*kh (=k). b64 packs.
      #pragma unroll
      for (int jt = 0; jt < 2; ++jt)
        #pragma unroll
        for (int it = 0; it < 2; ++it) {
          const int i_loc = wi * 2 + it, j_loc = wj * 2 + jt;
          const int grow = (i_loc & 3) * 8 + j_loc;        // rij & 31
          #pragma unroll
          for (int rg = 0; rg < 4; ++rg) {
            // 4 regs r=rg*4..+3 -> k = 8*rg + 4*kh + (0..3); hk = l31*32 + k
            const int G16 = l31 * 4 + rg;
            const int pos16 = G16 ^ (l31 & 7) ^ (grow & 7);
            __hip_bfloat162 lo = __float22bfloat162_rn(
                float2{acc[jt][it][rg * 4 + 0], acc[jt][it][rg * 4 + 1]});
            __hip_bfloat162 hi = __float22bfloat162_rn(
                float2{acc[jt][it][rg * 4 + 2], acc[jt][it][rg * 4 + 3]});
            union { __hip_bfloat162 h2[2]; uint2 u; } pk; pk.h2[0] = lo; pk.h2[1] = hi;
            *(uint2*)&Gs[grow * 1024 + pos16 * 8 + kh * 4] = pk.u;
          }
        }
    }
    __syncthreads();

    // stage B: wave = (kq = wv>>2, ph = (wv>>1)&1, rh = wv&1). 16x16x32.
    // rows grow = rh*16+l15; K-quarter [kq*256,+256); p-half ph.
    const int kq = wv >> 2, ph = (wv >> 1) & 1, rh = wv & 1;
    const int grow = rh * 16 + l15;
    const f32x4 fz4 = {0.f, 0.f, 0.f, 0.f};
    f32x4 ob[2] = {fz4, fz4};
    const u16* grow_base = Gs + grow * 1024;
    #pragma unroll 2
    for (int ks = 0; ks < 8; ++ks) {
      const int G16 = kq * 32 + ks * 4 + quad;
      const int pos16 = G16 ^ (ks & 7) ^ (grow & 7);       // phi = (hk>>5)&7 = ks
      const short8 ga = *(const short8*)&grow_base[pos16 * 8];
      #pragma unroll
      for (int nt = 0; nt < 2; ++nt) {
        const int p = ph * 32 + nt * 16 + l15;
        const short8 wf = *(const short8*)&W_t[(kq * 32 + ks * 4 + quad) * 512 + p * 8];
        ob[nt] = __builtin_amdgcn_mfma_f32_16x16x32_bf16(ga, wf, ob[nt], 0, 0, 0);
      }
    }
    __syncthreads();   // Gs reads done -> red may overwrite

    #pragma unroll
    for (int nt = 0; nt < 2; ++nt)
      #pragma unroll
      for (int r = 0; r < 4; ++r) {
        const int rij32 = rh * 16 + quad * 4 + r;
        const int p = ph * 32 + nt * 16 + l15;
        red[(kq * 32 + rij32) * 68 + p] = ob[nt][r];
      }
    __syncthreads();

    // reduce 4 kq partials + bias + store: thread t -> (rij32 = t>>5, 2 p)
    {
      const int rij32 = tid >> 5, p2 = (tid & 31) * 2;
      float2 s = {0.f, 0.f};
      #pragma unroll
      for (int q = 0; q < 4; ++q) {
        const float2 v = *(const float2*)&red[(q * 32 + rij32) * 68 + p2];
        s.x += v.x; s.y += v.y;
      }
      const float2 bo2 = ((const float2*)bo)[tid & 31];
      const int iG = iT * 8 + pass * 4 + (rij32 >> 3);
      const int jG = jT * 8 + (rij32 & 7);
      float2 o; o.x = s.x + bo2.x; o.y = s.y + bo2.y;
      *(float2*)&out[(iG * NDIM + jG) * PDIM + p2] = o;
    }
  }
}

extern "C" void kernel_launch(void* const* d_in, const int* in_sizes, int n_in,
                              void* d_out, int out_size, void* d_ws, size_t ws_size,
                              hipStream_t stream) {
  const float* msa   = (const float*)d_in[0];
  const float* mask  = (const float*)d_in[1];
  const float* gamma = (const float*)d_in[2];
  const float* beta  = (const float*)d_in[3];
  const float* Wa    = (const float*)d_in[4];
  const float* ba    = (const float*)d_in[5];
  const float* Wb    = (const float*)d_in[6];
  const float* bb    = (const float*)d_in[7];
  const float* Wo    = (const float*)d_in[8];
  const float* bo    = (const float*)d_in[9];

  char* ws = (char*)d_ws;
  u16* a_t = (u16*)ws;                       // 2 MB: [8192 ih][128 s] bf16 (pre-swizzled rows)
  u16* b_t = (u16*)(ws + (2u << 20));        // 2 MB: [8192 jk][128 s] bf16 (pre-swizzled rows)
  u16* W_t = (u16*)(ws + (4u << 20));        // 128 KB: [hk/8][p][hk%8] bf16

  k_pre<<<dim3(1024), dim3(256), 0, stream>>>(msa, mask, gamma, beta,
                                              Wa, ba, Wb, bb, Wo, a_t, b_t, W_t);
  k_fused<<<dim3(32, 32), dim3(1024), 0, stream>>>(a_t, b_t, W_t, bo, (float*)d_out);
}

// Round 8
// 116.174 us; speedup vs baseline: 1.0968x; 1.0968x over previous
//
#include <hip/hip_runtime.h>
#include <hip/hip_bf16.h>
#include <stdint.h>

typedef unsigned short u16;
typedef __attribute__((ext_vector_type(8))) short short8;
typedef __attribute__((ext_vector_type(4))) float f32x4;

#define NDIM 256
#define SDIM 128
#define DDIM 64
#define HDIM 32
#define PDIM 64
#define EPS 1e-5f

__device__ __forceinline__ u16 f2bf(float f) {
  union { float f; uint32_t u; } v; v.f = f;
  uint32_t r = v.u + 0x7fffu + ((v.u >> 16) & 1u);   // RNE
  return (u16)(r >> 16);
}

// ---------------- K1: LN + dual projection via MFMA ----------------
// grid 1024: block = (n = bid>>2, sq = bid&3 -> 32 s-rows). 256 thr = 4 waves.
// a_t/b_t rows PRE-SWIZZLED: element s of row c at position
// (s&64)|(((s>>3)&7)^(c&7))<<3|(s&7). Epilogue now goes through an LDS
// transpose so each thread issues ONE b128 global store (was 8 scalar u16).
__global__ __launch_bounds__(256, 4) void k_pre(
    const float* __restrict__ msa, const float* __restrict__ mask,
    const float* __restrict__ gamma, const float* __restrict__ beta,
    const float* __restrict__ Wa, const float* __restrict__ ba,
    const float* __restrict__ Wb, const float* __restrict__ bb,
    const float* __restrict__ Wo,
    u16* __restrict__ a_t, u16* __restrict__ b_t, u16* __restrict__ W_t)
{
  __shared__ u16 xs[32 * 64];        // [s][granule swizzled] 4KB X_norm bf16
  __shared__ u16 wt[64 * 64];        // [c][granule swizzled] 8KB W^T bf16
  __shared__ u16 oT[64 * 32];        // [c][s_local] 4KB output transpose
  __shared__ float psum[2][8][32];
  __shared__ float maskF[128];
  __shared__ float gbF[128];

  const int n = blockIdx.x >> 2, sq = blockIdx.x & 3;
  const int t = threadIdx.x, lane = t & 63, wv = t >> 6;
  const int l15 = lane & 15, quad = lane >> 4;

  if (t < 64) gbF[t] = gamma[t];
  else if (t < 128) gbF[t] = beta[t - 64];
  else maskF[t - 128] = mask[(t - 128) * NDIM + n];

  // LN partials: row sl (0..31), d-slice pt8 (8 floats); 8 thr share a row
  const int sl = t >> 3, pt8 = t & 7;
  float x[8];
  {
    const float* xr = msa + ((sq * 32 + sl) * NDIM + n) * DDIM + pt8 * 8;
    float sum = 0.f, sq2 = 0.f;
    #pragma unroll
    for (int i = 0; i < 2; ++i) {
      const float4 q = ((const float4*)xr)[i];
      x[4*i] = q.x; x[4*i+1] = q.y; x[4*i+2] = q.z; x[4*i+3] = q.w;
      sum += q.x + q.y + q.z + q.w;
      sq2 += q.x*q.x + q.y*q.y + q.z*q.z + q.w*q.w;
    }
    psum[0][pt8][sl] = sum;
    psum[1][pt8][sl] = sq2;
  }

  // W^T: col c = t&63, d-slice (t>>6)*16
  {
    const int c = t & 63, ds = t >> 6;
    const int c31 = c & 31;
    const float* Wsel = (c >> 5) ? Wb : Wa;
    float w[16];
    #pragma unroll
    for (int i = 0; i < 16; ++i) w[i] = Wsel[(ds * 16 + i) * HDIM + c31];
    #pragma unroll
    for (int jj = 0; jj < 2; ++jj) {
      short8 v;
      #pragma unroll
      for (int k = 0; k < 8; ++k) v[k] = (short)f2bf(w[jj * 8 + k]);
      *(short8*)&wt[c * 64 + (((ds * 2 + jj) ^ (c & 7)) << 3)] = v;
    }
  }
  __syncthreads();

  // finish LN
  {
    float s0 = 0.f, s1 = 0.f;
    #pragma unroll
    for (int q = 0; q < 8; ++q) { s0 += psum[0][q][sl]; s1 += psum[1][q][sl]; }
    const float mu = s0 * (1.f / 64.f);
    const float var = s1 * (1.f / 64.f) - mu * mu;
    const float rs = rsqrtf(var + EPS);
    short8 v;
    #pragma unroll
    for (int k = 0; k < 8; ++k) {
      const int d = pt8 * 8 + k;
      v[k] = (short)f2bf((x[k] - mu) * rs * gbF[d] + gbF[64 + d]);
    }
    *(short8*)&xs[sl * 64 + ((pt8 ^ (sl & 7)) << 3)] = v;
  }
  float m2 = maskF[lane] + maskF[64 + lane];
  #pragma unroll
  for (int m = 32; m; m >>= 1) m2 += __shfl_xor(m2, m, 64);
  const float dinv = 1.f / fmaxf(m2, 1.f);
  __syncthreads();

  // projection: D[m=c][n=s], wave wv = c-tile [wv*16,+16); s covers 32 (2 nt)
  const f32x4 fz = {0.f, 0.f, 0.f, 0.f};
  f32x4 acc[2] = {fz, fz};
  short8 af[2];
  #pragma unroll
  for (int ks = 0; ks < 2; ++ks)
    af[ks] = *(const short8*)&wt[(wv * 16 + l15) * 64 + (((ks * 4 + quad) ^ (l15 & 7)) << 3)];
  #pragma unroll
  for (int nt = 0; nt < 2; ++nt)
    #pragma unroll
    for (int ks = 0; ks < 2; ++ks) {
      const short8 bf = *(const short8*)&xs[(nt * 16 + l15) * 64 + (((ks * 4 + quad) ^ (l15 & 7)) << 3)];
      acc[nt] = __builtin_amdgcn_mfma_f32_16x16x32_bf16(af[ks], bf, acc[nt], 0, 0, 0);
    }

  // epilogue -> LDS transpose
  const float* bsel = (wv < 2) ? ba : bb;
  float bias_r[4];
  #pragma unroll
  for (int r = 0; r < 4; ++r) bias_r[r] = bsel[(wv & 1) * 16 + quad * 4 + r];
  #pragma unroll
  for (int nt = 0; nt < 2; ++nt) {
    const int s = sq * 32 + nt * 16 + l15;
    const int slcl = nt * 16 + l15;
    const float mval = maskF[s];
    const float scale = (wv < 2) ? mval * dinv : mval;
    #pragma unroll
    for (int r = 0; r < 4; ++r) {
      const int c31 = (wv & 1) * 16 + quad * 4 + r;
      const int c = ((wv < 2) ? 0 : 32) + c31;
      oT[c * 32 + slcl] = f2bf((acc[nt][r] + bias_r[r]) * scale);
    }
  }
  __syncthreads();

  // one b128 store per thread: thread -> (c = t>>2, granule gi = t&3)
  {
    const int c = t >> 2, gi = t & 3;
    const int c31 = c & 31;
    const int s0 = sq * 32 + gi * 8;
    u16* dst = ((c < 32) ? a_t : b_t) + n * 4096 + c31 * 128
             + (s0 & 64) + ((((s0 >> 3) & 7) ^ (c31 & 7)) << 3);
    *(short8*)dst = *(const short8*)&oT[c * 32 + gi * 8];
  }

  // W_t2[hk>>3][p][hk&7] = bf16(Wo[hk][p])
  if (blockIdx.x < 256) {
    const int f = blockIdx.x * 256 + t;        // f = hk*64 + p
    const int p = f & 63, hk = f >> 6;
    W_t[(hk >> 3) * 512 + p * 8 + (hk & 7)] = f2bf(Wo[f]);
  }
}

// ---------------- K2: fused outer-product GEMM + Wo contraction ----------------
// grid (32 jT, 32 iT) x 512 thr (8 waves: wi 0..3 ih-quarter, wj 0..1 jk-half).
// 128 KB dynamic LDS: As[256][64]+Bs[256][64] (64KB, stage A) aliased into
// Gs[64 rij][1024 hk] (128KB). Stage A = R6's proven 8x4 mfma16 blocking over
// K=128 (2 chunks, glds staging from pre-swizzled a_t/b_t). SINGLE dump of all
// 64 rij, SINGLE stage-B pass (wave=(kq 4, ph 2): M=64, N=32, K=256; W_t2 read
// once per block = 128 KB), one red exchange [4][64][68], one epilogue.
// Barriers: 8 (was 12); W L2 traffic halved.
__global__ __launch_bounds__(512, 2) void k_fused(
    const u16* __restrict__ a_t, const u16* __restrict__ b_t,
    const u16* __restrict__ W_t, const float* __restrict__ bo,
    float* __restrict__ out)
{
  extern __shared__ char smem[];
  u16* As = (u16*)smem;              // [256 ih][64 k] per chunk, 32KB
  u16* Bs = (u16*)(smem + 32768);    // [256 jk][64 k] per chunk, 32KB
  u16* Gs = (u16*)smem;              // [64 rij][1024 hk] swizzled, 128KB
  float* red = (float*)smem;         // [4 kq][64 rij][68] f32, 69.6KB

  const int tid = threadIdx.x, lane = tid & 63, wv = tid >> 6;
  const int l15 = lane & 15, quad = lane >> 4;
  const int wi = wv >> 1, wj = wv & 1;
  const int jT = blockIdx.x, iT = blockIdx.y;

  const u16* gA = a_t + iT * 256 * SDIM;
  const u16* gB = b_t + jT * 256 * SDIM;

  const f32x4 fz = {0.f, 0.f, 0.f, 0.f};
  f32x4 acc[8][4];                   // [jt][it]
  #pragma unroll
  for (int jt = 0; jt < 8; ++jt)
    #pragma unroll
    for (int it = 0; it < 4; ++it) acc[jt][it] = fz;

  const int sub8 = lane >> 3, g16 = lane & 7;

  for (int ch = 0; ch < 2; ++ch) {
    __syncthreads();
    #pragma unroll
    for (int i = 0; i < 4; ++i) {                // As: 256 rows, 8 rows/instr
      const int rbase = wv * 32 + i * 8;
      __builtin_amdgcn_global_load_lds(
          (const __attribute__((address_space(1))) void*)&gA[(rbase + sub8) * SDIM + ch * 64 + g16 * 8],
          (__attribute__((address_space(3))) void*)&As[rbase * 64], 16, 0, 0);
    }
    #pragma unroll
    for (int i = 0; i < 4; ++i) {                // Bs: 256 rows
      const int rbase = wv * 32 + i * 8;
      __builtin_amdgcn_global_load_lds(
          (const __attribute__((address_space(1))) void*)&gB[(rbase + sub8) * SDIM + ch * 64 + g16 * 8],
          (__attribute__((address_space(3))) void*)&Bs[rbase * 64], 16, 0, 0);
    }
    __syncthreads();
    #pragma unroll
    for (int ks = 0; ks < 2; ++ks) {
      const int g = ks * 4 + quad;
      short8 afr[4], bfr[8];
      #pragma unroll
      for (int it = 0; it < 4; ++it) {
        const int row = wi * 64 + it * 16 + l15;
        afr[it] = *(const short8*)&As[row * 64 + ((g ^ (row & 7)) << 3)];
      }
      #pragma unroll
      for (int jt = 0; jt < 8; ++jt) {
        const int row = wj * 128 + jt * 16 + l15;
        bfr[jt] = *(const short8*)&Bs[row * 64 + ((g ^ (row & 7)) << 3)];
      }
      #pragma unroll
      for (int jt = 0; jt < 8; ++jt)
        #pragma unroll
        for (int it = 0; it < 4; ++it)
          acc[jt][it] = __builtin_amdgcn_mfma_f32_16x16x32_bf16(bfr[jt], afr[it], acc[jt][it], 0, 0, 0);
    }
  }
  __syncthreads();   // all As/Bs reads done; Gs (aliases them) safe to write

  // single dump of all 64 rij. D[m=jk (quad*4+r)][n=ih (l15)]; b64 packs.
  #pragma unroll
  for (int jt = 0; jt < 8; ++jt)
    #pragma unroll
    for (int it = 0; it < 4; ++it) {
      const int rij = (wi * 2 + (it >> 1)) * 8 + wj * 4 + (jt >> 1);   // 0..63
      const int h = (it & 1) * 16 + l15;
      const int hk = h * 32 + (jt & 1) * 16 + quad * 4;
      const int g4 = hk >> 2;
      const int g4s = g4 ^ ((g4 >> 4) & 6) ^ ((rij & 7) << 1);
      __hip_bfloat162 lo = __float22bfloat162_rn(float2{acc[jt][it][0], acc[jt][it][1]});
      __hip_bfloat162 hi = __float22bfloat162_rn(float2{acc[jt][it][2], acc[jt][it][3]});
      union { __hip_bfloat162 h2[2]; uint2 u; } pk; pk.h2[0] = lo; pk.h2[1] = hi;
      *(uint2*)&Gs[rij * 1024 + (g4s << 2)] = pk.u;
    }
  __syncthreads();

  // single stage B: wave = (kq = wv>>1, ph = wv&1); M=64 (4 mt), N=32 (2 nt),
  // K = 256 hk (8 ks); W_t2 read exactly once per block.
  const int kq = wv >> 1, ph = wv & 1;
  f32x4 ob[4][2];
  #pragma unroll
  for (int mt = 0; mt < 4; ++mt)
    #pragma unroll
    for (int nt = 0; nt < 2; ++nt) ob[mt][nt] = fz;
  #pragma unroll 2
  for (int ks = 0; ks < 8; ++ks) {
    const int kb = kq * 32 + ks * 4 + quad;       // hk>>3
    const int g4e = kb * 2;
    short8 ga[4], wf[2];
    #pragma unroll
    for (int mt = 0; mt < 4; ++mt) {
      const int row = mt * 16 + l15;              // = rij
      const int go = (g4e ^ ((g4e >> 4) & 6) ^ ((row & 7) << 1)) << 2;
      ga[mt] = *(const short8*)&Gs[row * 1024 + go];
    }
    #pragma unroll
    for (int nt = 0; nt < 2; ++nt)
      wf[nt] = *(const short8*)&W_t[kb * 512 + (ph * 32 + nt * 16 + l15) * 8];
    #pragma unroll
    for (int mt = 0; mt < 4; ++mt)
      #pragma unroll
      for (int nt = 0; nt < 2; ++nt)
        ob[mt][nt] = __builtin_amdgcn_mfma_f32_16x16x32_bf16(ga[mt], wf[nt], ob[mt][nt], 0, 0, 0);
  }
  __syncthreads();   // all Gs reads done -> red may overwrite

  #pragma unroll
  for (int mt = 0; mt < 4; ++mt)
    #pragma unroll
    for (int nt = 0; nt < 2; ++nt)
      #pragma unroll
      for (int r = 0; r < 4; ++r) {
        const int rij = mt * 16 + quad * 4 + r;
        const int p = ph * 32 + nt * 16 + l15;
        red[(kq * 64 + rij) * 68 + p] = ob[mt][nt][r];
      }
  __syncthreads();

  // reduce 4 kq partials + bias + store: thread t -> (rij = t>>3, 8 p)
  {
    const int rij = tid >> 3, po = (tid & 7) * 8;
    f32x4 s0 = fz, s1 = fz;
    #pragma unroll
    for (int q = 0; q < 4; ++q) {
      s0 += *(const f32x4*)&red[(q * 64 + rij) * 68 + po];
      s1 += *(const f32x4*)&red[(q * 64 + rij) * 68 + po + 4];
    }
    const float4 bo0 = ((const float4*)bo)[(tid & 7) * 2];
    const float4 bo1 = ((const float4*)bo)[(tid & 7) * 2 + 1];
    const int iG = iT * 8 + (rij >> 3), jG = jT * 8 + (rij & 7);
    float* op = &out[(iG * NDIM + jG) * PDIM + po];
    float4 o0, o1;
    o0.x = s0[0] + bo0.x; o0.y = s0[1] + bo0.y; o0.z = s0[2] + bo0.z; o0.w = s0[3] + bo0.w;
    o1.x = s1[0] + bo1.x; o1.y = s1[1] + bo1.y; o1.z = s1[2] + bo1.z; o1.w = s1[3] + bo1.w;
    *(float4*)op = o0;
    *(float4*)(op + 4) = o1;
  }
}

extern "C" void kernel_launch(void* const* d_in, const int* in_sizes, int n_in,
                              void* d_out, int out_size, void* d_ws, size_t ws_size,
                              hipStream_t stream) {
  const float* msa   = (const float*)d_in[0];
  const float* mask  = (const float*)d_in[1];
  const float* gamma = (const float*)d_in[2];
  const float* beta  = (const float*)d_in[3];
  const float* Wa    = (const float*)d_in[4];
  const float* ba    = (const float*)d_in[5];
  const float* Wb    = (const float*)d_in[6];
  const float* bb    = (const float*)d_in[7];
  const float* Wo    = (const float*)d_in[8];
  const float* bo    = (const float*)d_in[9];

  char* ws = (char*)d_ws;
  u16* a_t = (u16*)ws;                       // 2 MB: [8192 ih][128 s] bf16 (pre-swizzled rows)
  u16* b_t = (u16*)(ws + (2u << 20));        // 2 MB: [8192 jk][128 s] bf16 (pre-swizzled rows)
  u16* W_t = (u16*)(ws + (4u << 20));        // 128 KB: [hk/8][p][hk%8] bf16

  static_cast<void>(hipFuncSetAttribute(
      reinterpret_cast<const void*>(&k_fused),
      hipFuncAttributeMaxDynamicSharedMemorySize, 131072));

  k_pre<<<dim3(1024), dim3(256), 0, stream>>>(msa, mask, gamma, beta,
                                              Wa, ba, Wb, bb, Wo, a_t, b_t, W_t);
  k_fused<<<dim3(32, 32), dim3(512), 131072, stream>>>(a_t, b_t, W_t, bo, (float*)d_out);
}